// Round 6
// baseline (257.580 us; speedup 1.0000x reference)
//
#include <hip/hip_runtime.h>
#include <math.h>

#define B_ 4
#define C_ 256
#define N_ 4096   // H*W
#define LDE 68    // ET row stride (ushorts) — verified, 0 conflicts
#define LDX 72    // prep LDS tile stride (ushorts)

typedef __attribute__((ext_vector_type(8))) short short8;
typedef __attribute__((ext_vector_type(4))) float f32x4;

__device__ inline ushort f2bf(float f) {
    uint u = __float_as_uint(f);
    return (ushort)((u + 0x7fffu + ((u >> 16) & 1u)) >> 16);   // RNE
}
__device__ inline float bf2f(ushort h) { return __uint_as_float(((uint)h) << 16); }

__device__ inline f32x4 mfma16(short8 a, short8 b, f32x4 c) {
    return __builtin_amdgcn_mfma_f32_16x16x32_bf16(a, b, c, 0, 0, 0);
}

// Fragment-order layouts (lane l <-> (row l&15, k-group l>>4); 16 B per lane):
//   xfrag[b][nt=0..255][kk=0..7][lane][8]   (X = bf16(fm+fd), k=c)
//   ffrag[b][nc=0..63][ct=0..15][k2=0..1][lane][8]  (Fd bf16, k=n within chunk)
__device__ inline size_t xfi(int b, int nt, int kk) {
    return (((size_t)(b * 256 + nt)) * 8 + kk) * 512;
}
__device__ inline size_t ffi(int b, int nc, int ct, int k2) {
    return ((((size_t)(b * 64 + nc)) * 16 + ct) * 2 + k2) * 512;
}

// ---------------------------------------------------------------------------
// P0: build xfrag + ffrag (MFMA-native order) + dg (fused diag, atomicAdd).
// ---------------------------------------------------------------------------
__global__ __launch_bounds__(256) void prep_kernel(const float* __restrict__ fm,
                                                   const float* __restrict__ fd,
                                                   ushort* __restrict__ xfrag,
                                                   ushort* __restrict__ ffrag,
                                                   float* __restrict__ dg) {
    __shared__ ushort xl[64][LDX];   // [c-local][n-local]
    __shared__ ushort fl[64][LDX];   // [c-local][n-local]
    const int b = blockIdx.z, c0 = blockIdx.y * 64, n0 = blockIdx.x * 64;
    const int t = threadIdx.x;
    const int n4 = (t & 15) * 4, cl = t >> 4;
    const size_t base = (size_t)b * C_ * N_;
    float dsum[4] = {0.f, 0.f, 0.f, 0.f};
    #pragma unroll
    for (int p = 0; p < 4; ++p) {
        const int cr = 16 * p + cl;
        const float4 m4 = *(const float4*)(fm + base + (size_t)(c0 + cr) * N_ + n0 + n4);
        const float4 d4 = *(const float4*)(fd + base + (size_t)(c0 + cr) * N_ + n0 + n4);
        ushort4 fo;
        fo.x = f2bf(d4.x); fo.y = f2bf(d4.y); fo.z = f2bf(d4.z); fo.w = f2bf(d4.w);
        *(ushort4*)(&fl[cr][n4]) = fo;
        ushort4 xo;
        xo.x = f2bf(m4.x + d4.x); xo.y = f2bf(m4.y + d4.y);
        xo.z = f2bf(m4.z + d4.z); xo.w = f2bf(m4.w + d4.w);
        *(ushort4*)(&xl[cr][n4]) = xo;
        float r0 = bf2f(xo.x), r1 = bf2f(xo.y), r2 = bf2f(xo.z), r3 = bf2f(xo.w);
        dsum[0] = fmaf(r0, r0, dsum[0]); dsum[1] = fmaf(r1, r1, dsum[1]);
        dsum[2] = fmaf(r2, r2, dsum[2]); dsum[3] = fmaf(r3, r3, dsum[3]);
    }
    #pragma unroll
    for (int j = 0; j < 4; ++j) {
        dsum[j] += __shfl_xor(dsum[j], 16, 64);
        dsum[j] += __shfl_xor(dsum[j], 32, 64);
    }
    if (((t >> 4) & 3) == 0) {
        #pragma unroll
        for (int j = 0; j < 4; ++j)
            atomicAdd(dg + b * N_ + n0 + n4 + j, dsum[j]);
    }
    __syncthreads();
    const int l = t & 63, tl = t >> 6;     // tl = local tile index 0..3
    {   // xfrag: lane l <- n-row 16*tl+(l&15), c ushorts 32*kk+8*(l>>4)
        const int nl = 16 * tl + (l & 15);
        #pragma unroll
        for (int j = 0; j < 2; ++j) {
            const int kk = (c0 >> 5) + j;
            const int cb = 32 * j + 8 * (l >> 4);
            ushort v[8];
            #pragma unroll
            for (int i = 0; i < 8; ++i) v[i] = xl[cb + i][nl];
            ushort* dst = xfrag + xfi(b, (n0 >> 4) + tl, kk) + l * 8;
            ushort4 v0 = {v[0], v[1], v[2], v[3]}, v1 = {v[4], v[5], v[6], v[7]};
            *(ushort4*)(dst) = v0; *(ushort4*)(dst + 4) = v1;
        }
    }
    {   // ffrag: lane l <- c-row 16*tl+(l&15), n ushorts 32*k2+8*(l>>4)
        const int row = 16 * tl + (l & 15);
        #pragma unroll
        for (int k2 = 0; k2 < 2; ++k2) {
            const int col = 32 * k2 + 8 * (l >> 4);
            const ushort4 a0 = *(const ushort4*)(&fl[row][col]);
            const ushort4 a1 = *(const ushort4*)(&fl[row][col + 4]);
            ushort* dst = ffrag + ffi(b, n0 >> 6, (c0 >> 4) + tl, k2) + l * 8;
            *(ushort4*)(dst) = a0; *(ushort4*)(dst + 4) = a1;
        }
    }
}

// ---------------------------------------------------------------------------
// K2: lg[n] = dg[n] + log( sum_m exp(S[n,m]-dg[n]) ).
// 1024 thr (16 waves, 4/SIMD), grid 256 (XCD-swizzled). Wave = (16-n strip
// nsub=w&3, m-stream offset mt=w>>2). af persistent; bn 1-ahead rotation.
// No loop barriers. 4 waves share each m-stream -> L1-served duplicates.
// ---------------------------------------------------------------------------
__global__ __launch_bounds__(1024, 4) void lsum_kernel(const ushort* __restrict__ xfrag,
                                                       const float* __restrict__ dg,
                                                       float* __restrict__ lg) {
    __shared__ float red[16][16];
    const int bid = blockIdx.x;
    const int b = (bid >> 1) & 3;
    const int n0 = ((((bid >> 3) << 1) | (bid & 1))) * 64;
    const int t = threadIdx.x, lane = t & 63, w = t >> 6;
    const int l15 = lane & 15, q = lane >> 4;
    const int nsub = w & 3, mt = w >> 2;

    short8 af[8];
    #pragma unroll
    for (int kk = 0; kk < 8; ++kk)
        af[kk] = *(const short8*)(xfrag + xfi(b, (n0 >> 4) + nsub, kk) + lane * 8);
    float dv[4];
    #pragma unroll
    for (int r = 0; r < 4; ++r)
        dv[r] = dg[b * N_ + n0 + 16 * nsub + 4 * q + r];

    short8 bn[8];
    #pragma unroll
    for (int kk = 0; kk < 8; ++kk)
        bn[kk] = *(const short8*)(xfrag + xfi(b, mt, kk) + lane * 8);

    float rs[4] = {0.f, 0.f, 0.f, 0.f};
    for (int mc = 0; mc < 64; ++mc) {
        const int MTn = (mc + 1 < 64) ? (mc + 1) * 4 + mt : mt;   // harmless wrap
        f32x4 a0 = {0.f, 0.f, 0.f, 0.f};
        #pragma unroll
        for (int kk = 0; kk < 8; ++kk) {
            a0 = mfma16(af[kk], bn[kk], a0);
            bn[kk] = *(const short8*)(xfrag + xfi(b, MTn, kk) + lane * 8);
        }
        #pragma unroll
        for (int r = 0; r < 4; ++r)
            rs[r] += __expf(a0[r] - dv[r]);
    }
    #pragma unroll
    for (int off = 1; off < 16; off <<= 1)
        #pragma unroll
        for (int r = 0; r < 4; ++r)
            rs[r] += __shfl_xor(rs[r], off, 64);
    if (l15 == 0) {
        #pragma unroll
        for (int r = 0; r < 4; ++r)
            red[w][4 * q + r] = rs[r];
    }
    __syncthreads();
    if (t < 64) {
        const int ns = t >> 4, nn = t & 15;
        const float s = red[ns][nn] + red[ns + 4][nn] + red[ns + 8][nn] + red[ns + 12][nn];
        const int gi = b * N_ + n0 + 16 * ns + nn;
        lg[gi] = dg[gi] + __logf(s);
    }
}

// ---------------------------------------------------------------------------
// K3: out[c,m] = sum_n fd[c,n]*exp(S[n,m]-g[n]) + fd[c,m]
// 1024 thr (16 waves, 4/SIMD), grid 256 (XCD-swizzled), m-tile 64.
// Phase A: wave (a=w&3, h=w>>2) computes one 16x16 S tile (bfr persistent,
// an 1-chunk-ahead rotation). Phase C: wave owns c-rows 16w..16w+15.
// ET dbuf LDS; ONE lgkm-only barrier per chunk (vmem stays in flight).
// ---------------------------------------------------------------------------
__global__ __launch_bounds__(1024, 4) void out_kernel(const ushort* __restrict__ xfrag,
                                                      const ushort* __restrict__ ffrag,
                                                      const float* __restrict__ gg,
                                                      const float* __restrict__ fd32,
                                                      float* __restrict__ outp) {
    __shared__ ushort ET[2][64][LDE];   // [buf][m-local][n-local]
    const int bid = blockIdx.x;
    const int b = (bid >> 1) & 3;
    const int m0 = ((((bid >> 3) << 1) | (bid & 1))) * 64;
    const int t = threadIdx.x, lane = t & 63, w = t >> 6;
    const int l15 = lane & 15, q = lane >> 4;
    const int a = w & 3, h = w >> 2;     // phase A: n-subtile a, m-tile h
    const size_t fb = (size_t)b * C_ * N_;

    short8 bfr[8];                       // persistent Xm B-frags (m-tile h)
    #pragma unroll
    for (int kk = 0; kk < 8; ++kk)
        bfr[kk] = *(const short8*)(xfrag + xfi(b, (m0 >> 4) + h, kk) + lane * 8);

    f32x4 acc[4];
    #pragma unroll
    for (int mt = 0; mt < 4; ++mt)
        acc[mt] = (f32x4){0.f, 0.f, 0.f, 0.f};

    short8 an[8];                        // A-frags, chunk 0
    #pragma unroll
    for (int kk = 0; kk < 8; ++kk)
        an[kk] = *(const short8*)(xfrag + xfi(b, a, kk) + lane * 8);
    float gn[4];
    #pragma unroll
    for (int r = 0; r < 4; ++r) gn[r] = gg[b * N_ + 16 * a + 4 * q + r];

    int p = 0;
    for (int n0c = 0; n0c < N_; n0c += 64, p ^= 1) {
        const int nc = n0c >> 6;
        // Fd A-frags for THIS chunk (used in phase C, far away)
        short8 fn[2];
        #pragma unroll
        for (int k2 = 0; k2 < 2; ++k2)
            fn[k2] = *(const short8*)(ffrag + ffi(b, nc, w, k2) + lane * 8);
        float gv[4];
        #pragma unroll
        for (int r = 0; r < 4; ++r) gv[r] = gn[r];
        const int nx = (n0c + 64 < N_) ? n0c + 64 : 0;   // harmless wrap
        #pragma unroll
        for (int r = 0; r < 4; ++r) gn[r] = gg[b * N_ + nx + 16 * a + 4 * q + r];

        // ---- phase A: S tile (a, h); rotate an[] to next chunk ----
        f32x4 s0 = {0.f, 0.f, 0.f, 0.f};
        #pragma unroll
        for (int kk = 0; kk < 8; ++kk) {
            s0 = mfma16(an[kk], bfr[kk], s0);
            an[kk] = *(const short8*)(xfrag + xfi(b, (nx >> 4) + a, kk) + lane * 8);
        }
        // ---- phase B: E^T = bf16(exp(S-g)) -> ET[p][m][n] ----
        ushort4 e0;
        e0.x = f2bf(__expf(s0[0] - gv[0])); e0.y = f2bf(__expf(s0[1] - gv[1]));
        e0.z = f2bf(__expf(s0[2] - gv[2])); e0.w = f2bf(__expf(s0[3] - gv[3]));
        *(ushort4*)(&ET[p][16 * h + l15][16 * a + 4 * q]) = e0;

        // lgkm-only barrier: ds ops drained, prefetch vmem stays in flight
        asm volatile("s_waitcnt lgkmcnt(0)\n\ts_barrier" ::: "memory");

        // ---- phase C: out[16w..+16][m0..+64] += Fd * E ----
        #pragma unroll
        for (int k2 = 0; k2 < 2; ++k2) {
            #pragma unroll
            for (int mt = 0; mt < 4; ++mt) {
                const short8 be = *(const short8*)(&ET[p][16 * mt + l15][32 * k2 + 8 * q]);
                acc[mt] = mfma16(fn[k2], be, acc[mt]);
            }
        }
    }
    // ---- epilogue: + fp32 residual ----
    #pragma unroll
    for (int mt = 0; mt < 4; ++mt)
        #pragma unroll
        for (int r = 0; r < 4; ++r) {
            const int c = 16 * w + 4 * q + r;
            const int m = m0 + 16 * mt + l15;
            const size_t o = fb + (size_t)c * N_ + m;
            outp[o] = acc[mt][r] + fd32[o];
        }
}

// ---------------------------------------------------------------------------
extern "C" void kernel_launch(void* const* d_in, const int* in_sizes, int n_in,
                              void* d_out, int out_size, void* d_ws, size_t ws_size,
                              hipStream_t stream) {
    const float* fm = (const float*)d_in[0];
    const float* fd = (const float*)d_in[1];
    float* outp = (float*)d_out;

    const size_t xb_elts = (size_t)B_ * N_ * C_;   // elements per frag array
    const size_t need = xb_elts * 2 * 2 + (size_t)B_ * N_ * 4 * 2;  // ~17 MB
    if (ws_size < need) return;

    ushort* xfrag = (ushort*)d_ws;
    ushort* ffrag = xfrag + xb_elts;
    float*  dg    = (float*)(ffrag + xb_elts);
    float*  lg    = dg + (size_t)B_ * N_;

    hipMemsetAsync(dg, 0, (size_t)B_ * N_ * sizeof(float), stream);
    prep_kernel<<<dim3(N_ / 64, C_ / 64, B_), 256, 0, stream>>>(fm, fd, xfrag, ffrag, dg);
    lsum_kernel<<<dim3(256), 1024, 0, stream>>>(xfrag, dg, lg);
    out_kernel<<<dim3(256), 1024, 0, stream>>>(xfrag, ffrag, lg, fd, outp);
}

// Round 7
// 187.578 us; speedup vs baseline: 1.3732x; 1.3732x over previous
//
#include <hip/hip_runtime.h>
#include <math.h>

#define B_ 4
#define C_ 256
#define N_ 4096   // H*W
#define LDE 68    // ET row stride (ushorts) — verified, 0 conflicts
#define LDX 72    // prep LDS tile stride (ushorts)

typedef __attribute__((ext_vector_type(8))) short short8;
typedef __attribute__((ext_vector_type(4))) float f32x4;

__device__ inline ushort f2bf(float f) {
    uint u = __float_as_uint(f);
    return (ushort)((u + 0x7fffu + ((u >> 16) & 1u)) >> 16);   // RNE
}
__device__ inline float bf2f(ushort h) { return __uint_as_float(((uint)h) << 16); }

__device__ inline f32x4 mfma16(short8 a, short8 b, f32x4 c) {
    return __builtin_amdgcn_mfma_f32_16x16x32_bf16(a, b, c, 0, 0, 0);
}
__device__ inline f32x4 mfma8(long a, long b, f32x4 c) {
    return __builtin_amdgcn_mfma_f32_16x16x32_fp8_fp8(a, b, c, 0, 0, 0);
}

// Fragment-order layouts (lane l <-> (row l&15, k-group l>>4)):
//   xfrag8[b][nt=0..255][kk=0..7][lane][8 fp8]      (X = fp8(fm+fd), k=c, 512 B/tile)
//   ffrag [b][nc=0..63][ct=0..15][k2=0..1][lane][8] (Fd bf16, k=n within chunk)
__device__ inline size_t xfi8(int b, int nt, int kk) {   // BYTE offset
    return (((size_t)(b * 256 + nt)) * 8 + kk) * 512;
}
__device__ inline size_t ffi(int b, int nc, int ct, int k2) {   // ushort offset
    return ((((size_t)(b * 64 + nc)) * 16 + ct) * 2 + k2) * 512;
}

// ---------------------------------------------------------------------------
// P0: build xfrag8 (fp8, MFMA-native) + ffrag (bf16) + dg (diag shift, fused).
// dg from bf16 x — only a shift; lg = dg + log(l) is shift-invariant.
// ---------------------------------------------------------------------------
__global__ __launch_bounds__(256) void prep_kernel(const float* __restrict__ fm,
                                                   const float* __restrict__ fd,
                                                   uchar* __restrict__ xfrag8,
                                                   ushort* __restrict__ ffrag,
                                                   float* __restrict__ dg) {
    __shared__ ushort xl[64][LDX];   // [c-local][n-local] bf16 X
    __shared__ ushort fl[64][LDX];   // [c-local][n-local] bf16 Fd
    const int b = blockIdx.z, c0 = blockIdx.y * 64, n0 = blockIdx.x * 64;
    const int t = threadIdx.x;
    const int n4 = (t & 15) * 4, cl = t >> 4;
    const size_t base = (size_t)b * C_ * N_;
    float dsum[4] = {0.f, 0.f, 0.f, 0.f};
    #pragma unroll
    for (int p = 0; p < 4; ++p) {
        const int cr = 16 * p + cl;
        const float4 m4 = *(const float4*)(fm + base + (size_t)(c0 + cr) * N_ + n0 + n4);
        const float4 d4 = *(const float4*)(fd + base + (size_t)(c0 + cr) * N_ + n0 + n4);
        ushort4 fo;
        fo.x = f2bf(d4.x); fo.y = f2bf(d4.y); fo.z = f2bf(d4.z); fo.w = f2bf(d4.w);
        *(ushort4*)(&fl[cr][n4]) = fo;
        ushort4 xo;
        xo.x = f2bf(m4.x + d4.x); xo.y = f2bf(m4.y + d4.y);
        xo.z = f2bf(m4.z + d4.z); xo.w = f2bf(m4.w + d4.w);
        *(ushort4*)(&xl[cr][n4]) = xo;
        float r0 = bf2f(xo.x), r1 = bf2f(xo.y), r2 = bf2f(xo.z), r3 = bf2f(xo.w);
        dsum[0] = fmaf(r0, r0, dsum[0]); dsum[1] = fmaf(r1, r1, dsum[1]);
        dsum[2] = fmaf(r2, r2, dsum[2]); dsum[3] = fmaf(r3, r3, dsum[3]);
    }
    #pragma unroll
    for (int j = 0; j < 4; ++j) {
        dsum[j] += __shfl_xor(dsum[j], 16, 64);
        dsum[j] += __shfl_xor(dsum[j], 32, 64);
    }
    if (((t >> 4) & 3) == 0) {
        #pragma unroll
        for (int j = 0; j < 4; ++j)
            atomicAdd(dg + b * N_ + n0 + n4 + j, dsum[j]);
    }
    __syncthreads();
    const int l = t & 63, tl = t >> 6;     // tl = local tile index 0..3
    {   // xfrag8: lane l <- n-row 16*tl+(l&15), c bytes 32*kk+8*(l>>4), fp8 pack
        const int nl = 16 * tl + (l & 15);
        #pragma unroll
        for (int j = 0; j < 2; ++j) {
            const int kk = (c0 >> 5) + j;
            const int cb = 32 * j + 8 * (l >> 4);
            float f[8];
            #pragma unroll
            for (int i = 0; i < 8; ++i) f[i] = bf2f(xl[cb + i][nl]);
            int d0 = __builtin_amdgcn_cvt_pk_fp8_f32(f[0], f[1], 0, 0);
            d0 = __builtin_amdgcn_cvt_pk_fp8_f32(f[2], f[3], d0, 1);
            int d1 = __builtin_amdgcn_cvt_pk_fp8_f32(f[4], f[5], 0, 0);
            d1 = __builtin_amdgcn_cvt_pk_fp8_f32(f[6], f[7], d1, 1);
            uint* dst = (uint*)(xfrag8 + xfi8(b, (n0 >> 4) + tl, kk) + (size_t)l * 8);
            dst[0] = (uint)d0; dst[1] = (uint)d1;
        }
    }
    {   // ffrag: lane l <- c-row 16*tl+(l&15), n ushorts 32*k2+8*(l>>4)
        const int row = 16 * tl + (l & 15);
        #pragma unroll
        for (int k2 = 0; k2 < 2; ++k2) {
            const int col = 32 * k2 + 8 * (l >> 4);
            const ushort4 a0 = *(const ushort4*)(&fl[row][col]);
            const ushort4 a1 = *(const ushort4*)(&fl[row][col + 4]);
            ushort* dst = ffrag + ffi(b, n0 >> 6, (c0 >> 4) + tl, k2) + l * 8;
            *(ushort4*)(dst) = a0; *(ushort4*)(dst + 4) = a1;
        }
    }
}

// ---------------------------------------------------------------------------
// K2: lg[n] = dg[n] + log( sum_m exp(S[n,m]-dg[n]) ).  FP8 Gram, zero dup.
// 512 thr (8 waves), grid 256 (XCD-swizzled). Wave holds ALL 64 n-rows'
// A-frags persistent (fp8: 64 VGPR) and owns m-stream w: 8 distinct streams,
// 128 m per iter, 32 iters, no loop barriers, bn 1-ahead rotation.
// ---------------------------------------------------------------------------
__global__ __launch_bounds__(512, 2) void lsum_kernel(const uchar* __restrict__ xfrag8,
                                                      const float* __restrict__ dg,
                                                      float* __restrict__ lg) {
    __shared__ float red[8][64];
    const int bid = blockIdx.x;
    const int b = (bid >> 1) & 3;
    const int n0 = ((((bid >> 3) << 1) | (bid & 1))) * 64;
    const int t = threadIdx.x, lane = t & 63, w = t >> 6;
    const int l15 = lane & 15, q = lane >> 4;

    long af[4][8];
    #pragma unroll
    for (int ns = 0; ns < 4; ++ns)
        #pragma unroll
        for (int kk = 0; kk < 8; ++kk)
            af[ns][kk] = *(const long*)(xfrag8 + xfi8(b, (n0 >> 4) + ns, kk) + (size_t)lane * 8);
    float dv[4][4];
    #pragma unroll
    for (int ns = 0; ns < 4; ++ns)
        #pragma unroll
        for (int r = 0; r < 4; ++r)
            dv[ns][r] = dg[b * N_ + n0 + 16 * ns + 4 * q + r];

    long bn[8];
    #pragma unroll
    for (int kk = 0; kk < 8; ++kk)
        bn[kk] = *(const long*)(xfrag8 + xfi8(b, w, kk) + (size_t)lane * 8);

    float rs[4][4] = {};
    for (int mc = 0; mc < 32; ++mc) {
        const int mtn = (mc + 1 < 32) ? (mc + 1) * 8 + w : w;   // harmless wrap
        f32x4 a0 = {0.f,0.f,0.f,0.f}, a1 = {0.f,0.f,0.f,0.f};
        f32x4 a2 = {0.f,0.f,0.f,0.f}, a3 = {0.f,0.f,0.f,0.f};
        #pragma unroll
        for (int kk = 0; kk < 8; ++kk) {
            const long bc = bn[kk];
            a0 = mfma8(af[0][kk], bc, a0);
            a1 = mfma8(af[1][kk], bc, a1);
            a2 = mfma8(af[2][kk], bc, a2);
            a3 = mfma8(af[3][kk], bc, a3);
            bn[kk] = *(const long*)(xfrag8 + xfi8(b, mtn, kk) + (size_t)lane * 8);
        }
        #pragma unroll
        for (int r = 0; r < 4; ++r) {
            rs[0][r] += __expf(a0[r] - dv[0][r]);
            rs[1][r] += __expf(a1[r] - dv[1][r]);
            rs[2][r] += __expf(a2[r] - dv[2][r]);
            rs[3][r] += __expf(a3[r] - dv[3][r]);
        }
    }
    #pragma unroll
    for (int off = 1; off < 16; off <<= 1)
        #pragma unroll
        for (int ns = 0; ns < 4; ++ns)
            #pragma unroll
            for (int r = 0; r < 4; ++r)
                rs[ns][r] += __shfl_xor(rs[ns][r], off, 64);
    if (l15 == 0) {
        #pragma unroll
        for (int ns = 0; ns < 4; ++ns)
            #pragma unroll
            for (int r = 0; r < 4; ++r)
                red[w][16 * ns + 4 * q + r] = rs[ns][r];
    }
    __syncthreads();
    if (t < 64) {
        float s = 0.f;
        #pragma unroll
        for (int ww = 0; ww < 8; ++ww) s += red[ww][t];
        const int gi = b * N_ + n0 + t;
        lg[gi] = dg[gi] + __logf(s);
    }
}

// ---------------------------------------------------------------------------
// K3: out[c,m] = sum_n fd[c,n]*exp(S[n,m]-g[n]) + fd[c,m]
// Round-5 structure: 512 thr, grid 256 (XCD-swizzled), m-tile 64.
// Phase A now FP8 (halved an/bfr bytes). Xm B-frags persistent; Xn A-frags
// 1-chunk rotation; Fd bf16 top-of-chunk; ET dbuf LDS; ONE lgkm-only
// barrier per chunk (prefetch vmem stays in flight).
// ---------------------------------------------------------------------------
__global__ __launch_bounds__(512, 2) void out_kernel(const uchar* __restrict__ xfrag8,
                                                     const ushort* __restrict__ ffrag,
                                                     const float* __restrict__ gg,
                                                     const float* __restrict__ fd32,
                                                     float* __restrict__ outp) {
    __shared__ ushort ET[2][64][LDE];   // [buf][m-local][n-local]
    const int bid = blockIdx.x;
    const int b = (bid >> 1) & 3;
    const int m0 = ((((bid >> 3) << 1) | (bid & 1))) * 64;
    const int t = threadIdx.x, lane = t & 63, w = t >> 6;
    const int l15 = lane & 15, q = lane >> 4;
    const int a = w & 3, h = w >> 2;     // phase A: n-subtile a, m-pair h
    const size_t fb = (size_t)b * C_ * N_;

    long bfr[2][8];                      // persistent Xm B-frags (fp8)
    #pragma unroll
    for (int jt = 0; jt < 2; ++jt)
        #pragma unroll
        for (int kk = 0; kk < 8; ++kk)
            bfr[jt][kk] = *(const long*)(xfrag8 + xfi8(b, (m0 >> 4) + 2 * h + jt, kk) + (size_t)lane * 8);

    f32x4 acc[2][4];
    #pragma unroll
    for (int ct = 0; ct < 2; ++ct)
        #pragma unroll
        for (int mt = 0; mt < 4; ++mt)
            acc[ct][mt] = (f32x4){0.f, 0.f, 0.f, 0.f};

    long an[8];                          // Xn A-frags (fp8), chunk 0
    #pragma unroll
    for (int kk = 0; kk < 8; ++kk)
        an[kk] = *(const long*)(xfrag8 + xfi8(b, a, kk) + (size_t)lane * 8);
    float gn[4];
    #pragma unroll
    for (int r = 0; r < 4; ++r) gn[r] = gg[b * N_ + 16 * a + 4 * q + r];

    int p = 0;
    for (int n0c = 0; n0c < N_; n0c += 64, p ^= 1) {
        const int nc = n0c >> 6;
        // Fd A-frags (bf16) for THIS chunk — used in phase C, far away
        short8 fn[2][2];
        #pragma unroll
        for (int ct = 0; ct < 2; ++ct)
            #pragma unroll
            for (int k2 = 0; k2 < 2; ++k2)
                fn[ct][k2] = *(const short8*)(ffrag + ffi(b, nc, 2 * w + ct, k2) + lane * 8);
        float gv[4];
        #pragma unroll
        for (int r = 0; r < 4; ++r) gv[r] = gn[r];
        const int nx = (n0c + 64 < N_) ? n0c + 64 : 0;   // harmless wrap
        #pragma unroll
        for (int r = 0; r < 4; ++r) gn[r] = gg[b * N_ + nx + 16 * a + 4 * q + r];

        // ---- phase A (fp8): S tiles (a, 2h), (a, 2h+1); rotate an[] ----
        f32x4 s0 = {0.f, 0.f, 0.f, 0.f}, s1 = {0.f, 0.f, 0.f, 0.f};
        #pragma unroll
        for (int kk = 0; kk < 8; ++kk) {
            s0 = mfma8(an[kk], bfr[0][kk], s0);
            s1 = mfma8(an[kk], bfr[1][kk], s1);
            an[kk] = *(const long*)(xfrag8 + xfi8(b, (nx >> 4) + a, kk) + (size_t)lane * 8);
        }
        // ---- phase B: E^T = bf16(exp(S-g)) -> ET[p][m][n] ----
        ushort4 e0, e1;
        e0.x = f2bf(__expf(s0[0] - gv[0])); e0.y = f2bf(__expf(s0[1] - gv[1]));
        e0.z = f2bf(__expf(s0[2] - gv[2])); e0.w = f2bf(__expf(s0[3] - gv[3]));
        e1.x = f2bf(__expf(s1[0] - gv[0])); e1.y = f2bf(__expf(s1[1] - gv[1]));
        e1.z = f2bf(__expf(s1[2] - gv[2])); e1.w = f2bf(__expf(s1[3] - gv[3]));
        *(ushort4*)(&ET[p][32 * h + l15][16 * a + 4 * q])      = e0;
        *(ushort4*)(&ET[p][32 * h + 16 + l15][16 * a + 4 * q]) = e1;

        // lgkm-only barrier: ds ops drained, prefetch vmem stays in flight
        asm volatile("s_waitcnt lgkmcnt(0)\n\ts_barrier" ::: "memory");

        // ---- phase C (bf16): out[32w..+32][m0..+64] += Fd * E ----
        #pragma unroll
        for (int k2 = 0; k2 < 2; ++k2) {
            #pragma unroll
            for (int mt = 0; mt < 4; ++mt) {
                const short8 be = *(const short8*)(&ET[p][16 * mt + l15][32 * k2 + 8 * q]);
                acc[0][mt] = mfma16(fn[0][k2], be, acc[0][mt]);
                acc[1][mt] = mfma16(fn[1][k2], be, acc[1][mt]);
            }
        }
    }
    // ---- epilogue: + fp32 residual ----
    #pragma unroll
    for (int ct = 0; ct < 2; ++ct)
        #pragma unroll
        for (int mt = 0; mt < 4; ++mt)
            #pragma unroll
            for (int r = 0; r < 4; ++r) {
                const int c = 32 * w + 16 * ct + 4 * q + r;
                const int m = m0 + 16 * mt + l15;
                const size_t o = fb + (size_t)c * N_ + m;
                outp[o] = acc[ct][mt][r] + fd32[o];
            }
}

// ---------------------------------------------------------------------------
extern "C" void kernel_launch(void* const* d_in, const int* in_sizes, int n_in,
                              void* d_out, int out_size, void* d_ws, size_t ws_size,
                              hipStream_t stream) {
    const float* fm = (const float*)d_in[0];
    const float* fd = (const float*)d_in[1];
    float* outp = (float*)d_out;

    const size_t xb_elts = (size_t)B_ * N_ * C_;                    // 4.19M
    const size_t need = xb_elts + xb_elts * 2 + (size_t)B_ * N_ * 8; // ~12.7 MB
    if (ws_size < need) return;

    uchar*  xfrag8 = (uchar*)d_ws;                    // fp8, 4.19 MB
    ushort* ffrag  = (ushort*)(xfrag8 + xb_elts);     // bf16, 8.39 MB
    float*  dg     = (float*)(ffrag + xb_elts);
    float*  lg     = dg + (size_t)B_ * N_;

    hipMemsetAsync(dg, 0, (size_t)B_ * N_ * sizeof(float), stream);
    prep_kernel<<<dim3(N_ / 64, C_ / 64, B_), 256, 0, stream>>>(fm, fd, xfrag8, ffrag, dg);
    lsum_kernel<<<dim3(256), 512, 0, stream>>>(xfrag8, dg, lg);
    out_kernel<<<dim3(256), 512, 0, stream>>>(xfrag8, ffrag, lg, fd, outp);
}